// Round 3
// baseline (687.030 us; speedup 1.0000x reference)
//
#include <hip/hip_runtime.h>

#define NNODES 1700
#define CDIM   256

typedef __attribute__((ext_vector_type(8))) short bf16x8;
typedef __attribute__((ext_vector_type(4))) float f32x4;

__device__ inline float bf2f(unsigned h) { return __uint_as_float(h << 16); }
__device__ inline unsigned short f2bf(float f) {
  unsigned u = __float_as_uint(f);
  u = (u + 0x7FFFu + ((u >> 16) & 1u)) >> 16;  // RNE
  return (unsigned short)u;
}

// ---------------- graph preprocessing ----------------

__global__ void zero_kernel(int* p, int n) {
  int i = blockIdx.x * blockDim.x + threadIdx.x;
  if (i < n) p[i] = 0;
}

// edge_index layout [2, E] row-major: sources [0..E), destinations [E..2E)
__global__ void count_kernel(const int* __restrict__ ei, int E, int* __restrict__ cnt) {
  int i = blockIdx.x * blockDim.x + threadIdx.x;
  if (i < E) atomicAdd(&cnt[ei[E + i]], 1);
}

__global__ void dinv_kernel(const int* __restrict__ cnt, float* __restrict__ dinv, int n) {
  int i = blockIdx.x * blockDim.x + threadIdx.x;
  if (i < n) dinv[i] = rsqrtf((float)(cnt[i] + 1));  // +1 self-loop; deg >= 1
}

// exclusive scan of (cnt[i]+1) over N=1700 -> off[0..N]; single block, 1024 thr, 2048 slots
__global__ __launch_bounds__(1024) void scan_kernel(const int* __restrict__ cnt, int n,
                                                    int* __restrict__ off) {
  __shared__ int s[2048];
  int t = threadIdx.x;
  for (int i = t; i < 2048; i += 1024) s[i] = (i < n) ? (cnt[i] + 1) : 0;
  for (int d = 1; d < 2048; d <<= 1) {
    __syncthreads();
    int idx = (t + 1) * (d << 1) - 1;
    if (idx < 2048) s[idx] += s[idx - d];
  }
  __syncthreads();
  if (t == 0) s[2047] = 0;
  for (int d = 1024; d >= 1; d >>= 1) {
    __syncthreads();
    int idx = (t + 1) * (d << 1) - 1;
    if (idx < 2048) { int tmp = s[idx - d]; s[idx - d] = s[idx]; s[idx] += tmp; }
  }
  __syncthreads();
  for (int i = t; i <= n; i += 1024) off[i] = s[i];
}

__global__ void fill_kernel(const int* __restrict__ ei, int E, int n,
                            const float* __restrict__ dinv, const int* __restrict__ off,
                            int* __restrict__ cursor, int* __restrict__ srcv,
                            float* __restrict__ wv) {
  int i = blockIdx.x * blockDim.x + threadIdx.x;
  if (i >= E + n) return;
  int s, d;
  if (i < E) { s = ei[i]; d = ei[E + i]; } else { s = d = i - E; }
  float w = dinv[s] * dinv[d];
  int p = atomicAdd(&cursor[d], 1);
  int idx = off[d] + p;
  srcv[idx] = s;
  wv[idx] = w;
}

// W f32 [k][n] -> Wtt bf16 K-tiled [s][n][32]  (s = k/32)
__global__ void transpose_kernel(const float* __restrict__ W,
                                 unsigned short* __restrict__ Wtt) {
  int i = blockIdx.x * 256 + threadIdx.x;  // 65536 elems
  int k = i >> 8, n = i & 255;
  Wtt[(((k >> 5) << 8) + n) * 32 + (k & 31)] = f2bf(W[i]);
}

// ---------------- fused layer: out = act(Â·Src·W + bias [+resid]) ----------------
// One block = 128 global rows. Phase 1: VALU-aggregate Â·Src (f32 accum) -> bf16 As (LDS,
// K-tiled [8][128][32], 16B units XOR-swizzled by row&3). Phase 2: 4 waves, each 64x128
// output; A-frags from LDS, B-frags direct from global (L2-resident Wtt), NO k-loop
// barriers. Epilogue fuses bias+relu (+f32 residual / f32 out on FINAL).

template <bool SRC_F32, bool FINAL>
__global__ __launch_bounds__(256, 2) void gcn_layer(
    const void* __restrict__ Src, const unsigned short* __restrict__ Wtt,
    const int* __restrict__ off, const int* __restrict__ srcv,
    const float* __restrict__ wv, const float* __restrict__ bias,
    const float* __restrict__ resid, void* __restrict__ Out) {
  __shared__ __align__(16) unsigned short As[8 * 128 * 32];  // 64 KB
  const int t = threadIdx.x;
  const int row0 = blockIdx.x * 128;

  // ---- phase 1: aggregation into As ----
#pragma unroll
  for (int j = 0; j < 4; j++) {
    const int s = ((t >> 4) & 3) | ((j & 1) << 2);
    const int r = (t & 15) | (((t >> 6) & 3) << 4) | ((j >> 1) << 6);
    const int grow = row0 + r;
    const int b = grow / NNODES;
    const int n = grow - b * NNODES;
    const int beg = off[n], end = off[n + 1];
    float acc[32];
#pragma unroll
    for (int c = 0; c < 32; c++) acc[c] = 0.f;
    for (int e = beg; e < end; e++) {
      const int sr = b * NNODES + srcv[e];
      const float w = wv[e];
      if (SRC_F32) {
        const float* p = (const float*)Src + (size_t)sr * CDIM + s * 32;
#pragma unroll
        for (int c4 = 0; c4 < 8; c4++) {
          float4 v = *(const float4*)(p + c4 * 4);
          acc[c4 * 4 + 0] += w * v.x; acc[c4 * 4 + 1] += w * v.y;
          acc[c4 * 4 + 2] += w * v.z; acc[c4 * 4 + 3] += w * v.w;
        }
      } else {
        const unsigned short* p = (const unsigned short*)Src + (size_t)sr * CDIM + s * 32;
#pragma unroll
        for (int c8 = 0; c8 < 4; c8++) {
          uint4 v = *(const uint4*)(p + c8 * 8);
          acc[c8 * 8 + 0] += w * bf2f(v.x & 0xffffu); acc[c8 * 8 + 1] += w * bf2f(v.x >> 16);
          acc[c8 * 8 + 2] += w * bf2f(v.y & 0xffffu); acc[c8 * 8 + 3] += w * bf2f(v.y >> 16);
          acc[c8 * 8 + 4] += w * bf2f(v.z & 0xffffu); acc[c8 * 8 + 5] += w * bf2f(v.z >> 16);
          acc[c8 * 8 + 6] += w * bf2f(v.w & 0xffffu); acc[c8 * 8 + 7] += w * bf2f(v.w >> 16);
        }
      }
    }
    unsigned short* base = &As[((s << 7) + r) << 5];
#pragma unroll
    for (int u = 0; u < 4; u++) {
      const int pu = u ^ (r & 3);  // swizzle 16B units
      bf16x8 pk;
#pragma unroll
      for (int c = 0; c < 8; c++) pk[c] = (short)f2bf(acc[u * 8 + c]);
      *(bf16x8*)(base + (pu << 3)) = pk;
    }
  }
  __syncthreads();  // the only barrier

  // ---- phase 2: GEMM, wave tile 64 rows x 128 cols ----
  const int lane = t & 63, w = t >> 6;
  const int wm = (w & 1) * 64, wn = (w >> 1) * 128;
  const int rl = lane & 15, q = lane >> 4;
  f32x4 acc[4][8];
#pragma unroll
  for (int mi = 0; mi < 4; mi++)
#pragma unroll
    for (int ni = 0; ni < 8; ni++) acc[mi][ni] = (f32x4){0.f, 0.f, 0.f, 0.f};

  const int swq = (q ^ (rl & 3)) << 3;  // swizzled unit offset (r&3 == rl&3 for all mi)
  for (int s = 0; s < 8; s++) {
    bf16x8 a[4];
#pragma unroll
    for (int mi = 0; mi < 4; mi++) {
      const int r = wm + mi * 16 + rl;
      a[mi] = *(const bf16x8*)&As[(((s << 7) + r) << 5) + swq];
    }
#pragma unroll
    for (int ni = 0; ni < 8; ni++) {
      const int n = wn + ni * 16 + rl;
      bf16x8 bfr = *(const bf16x8*)&Wtt[((s << 8) + n) * 32 + (q << 3)];
#pragma unroll
      for (int mi = 0; mi < 4; mi++)
        acc[mi][ni] = __builtin_amdgcn_mfma_f32_16x16x32_bf16(a[mi], bfr, acc[mi][ni], 0, 0, 0);
    }
  }

  // ---- epilogue ----
  float bv[8];
#pragma unroll
  for (int ni = 0; ni < 8; ni++) bv[ni] = bias[wn + ni * 16 + rl];
  const int orow = q * 4;
#pragma unroll
  for (int mi = 0; mi < 4; mi++) {
#pragma unroll
    for (int ni = 0; ni < 8; ni++) {
      const int col = wn + ni * 16 + rl;
#pragma unroll
      for (int rr = 0; rr < 4; rr++) {
        const int grow = row0 + wm + mi * 16 + orow + rr;
        const size_t o = (size_t)grow * CDIM + col;
        float v = acc[mi][ni][rr] + bv[ni];
        if (FINAL) {
          v += resid[o];
          ((float*)Out)[o] = fmaxf(v, 0.f);
        } else {
          ((unsigned short*)Out)[o] = f2bf(fmaxf(v, 0.f));
        }
      }
    }
  }
}

// ---------------- launch ----------------

extern "C" void kernel_launch(void* const* d_in, const int* in_sizes, int n_in,
                              void* d_out, int out_size, void* d_ws, size_t ws_size,
                              hipStream_t stream) {
  const float* x  = (const float*)d_in[0];
  const float* W1 = (const float*)d_in[1];
  const float* b1 = (const float*)d_in[2];
  const float* W2 = (const float*)d_in[3];
  const float* b2 = (const float*)d_in[4];
  const float* W3 = (const float*)d_in[5];
  const float* b3 = (const float*)d_in[6];
  const int* esp = (const int*)d_in[7];
  const int* etm = (const int*)d_in[8];

  const int Esp = in_sizes[7] / 2;
  const int Etm = in_sizes[8] / 2;
  const int B = in_sizes[0] / (NNODES * CDIM);
  const int M = B * NNODES;

  char* ws = (char*)d_ws;
  size_t woff = 0;
  auto alloc = [&](size_t bytes) -> void* {
    void* p = ws + woff;
    woff = (woff + bytes + 255) & ~(size_t)255;
    return p;
  };

  unsigned short* Act1 = (unsigned short*)alloc((size_t)M * CDIM * 2);  // 55.7 MB
  unsigned short* Act2 = (unsigned short*)alloc((size_t)M * CDIM * 2);  // 55.7 MB
  unsigned short* Wtt  = (unsigned short*)alloc((size_t)3 * CDIM * CDIM * 2);
  int* zero_base = (int*)alloc((size_t)4 * NNODES * sizeof(int));
  int* cnt_sp = zero_base;
  int* cur_sp = zero_base + NNODES;
  int* cnt_tm = zero_base + 2 * NNODES;
  int* cur_tm = zero_base + 3 * NNODES;
  int* off_sp = (int*)alloc((NNODES + 1) * sizeof(int));
  int* off_tm = (int*)alloc((NNODES + 1) * sizeof(int));
  float* dinv_sp = (float*)alloc(NNODES * sizeof(float));
  float* dinv_tm = (float*)alloc(NNODES * sizeof(float));
  int*   src_sp = (int*)alloc((size_t)(Esp + NNODES) * sizeof(int));
  float* wgt_sp = (float*)alloc((size_t)(Esp + NNODES) * sizeof(float));
  int*   src_tm = (int*)alloc((size_t)(Etm + NNODES) * sizeof(int));
  float* wgt_tm = (float*)alloc((size_t)(Etm + NNODES) * sizeof(float));

  zero_kernel<<<(4 * NNODES + 255) / 256, 256, 0, stream>>>(zero_base, 4 * NNODES);
  transpose_kernel<<<256, 256, 0, stream>>>(W1, Wtt);
  transpose_kernel<<<256, 256, 0, stream>>>(W2, Wtt + CDIM * CDIM);
  transpose_kernel<<<256, 256, 0, stream>>>(W3, Wtt + 2 * CDIM * CDIM);
  count_kernel<<<(Esp + 255) / 256, 256, 0, stream>>>(esp, Esp, cnt_sp);
  count_kernel<<<(Etm + 255) / 256, 256, 0, stream>>>(etm, Etm, cnt_tm);
  dinv_kernel<<<(NNODES + 255) / 256, 256, 0, stream>>>(cnt_sp, dinv_sp, NNODES);
  dinv_kernel<<<(NNODES + 255) / 256, 256, 0, stream>>>(cnt_tm, dinv_tm, NNODES);
  scan_kernel<<<1, 1024, 0, stream>>>(cnt_sp, NNODES, off_sp);
  scan_kernel<<<1, 1024, 0, stream>>>(cnt_tm, NNODES, off_tm);
  fill_kernel<<<(Esp + NNODES + 255) / 256, 256, 0, stream>>>(esp, Esp, NNODES, dinv_sp,
                                                              off_sp, cur_sp, src_sp, wgt_sp);
  fill_kernel<<<(Etm + NNODES + 255) / 256, 256, 0, stream>>>(etm, Etm, NNODES, dinv_tm,
                                                              off_tm, cur_tm, src_tm, wgt_tm);

  const int nblk = M / 128;  // 850

  // layer 1 (spatial):  Act1 = relu((Â x) W1 + b1)
  gcn_layer<true, false><<<nblk, 256, 0, stream>>>(x, Wtt, off_sp, src_sp, wgt_sp, b1,
                                                   nullptr, Act1);
  // layer 2 (temporal): Act2 = relu((Â Act1) W2 + b2)
  gcn_layer<false, false><<<nblk, 256, 0, stream>>>(Act1, Wtt + CDIM * CDIM, off_tm, src_tm,
                                                    wgt_tm, b2, nullptr, Act2);
  // layer 3 (spatial) + residual -> f32 out
  gcn_layer<false, true><<<nblk, 256, 0, stream>>>(Act2, Wtt + 2 * CDIM * CDIM, off_sp,
                                                   src_sp, wgt_sp, b3, x, d_out);
}

// Round 4
// 510.541 us; speedup vs baseline: 1.3457x; 1.3457x over previous
//
#include <hip/hip_runtime.h>

#define NNODES 1700
#define CDIM   256
#define NB     64  // batch (fixed by problem: in_sizes[0] = 64*1700*256)

typedef __attribute__((ext_vector_type(8))) short bf16x8;
typedef __attribute__((ext_vector_type(4))) float f32x4;

__device__ inline float bf2f(unsigned h) { return __uint_as_float(h << 16); }
__device__ inline unsigned short f2bf(float f) {
  unsigned u = __float_as_uint(f);
  u = (u + 0x7FFFu + ((u >> 16) & 1u)) >> 16;  // RNE
  return (unsigned short)u;
}

__device__ inline void async_copy16(const void* gsrc, void* ldst) {
  __builtin_amdgcn_global_load_lds(
      (const __attribute__((address_space(1))) unsigned int*)gsrc,
      (__attribute__((address_space(3))) unsigned int*)ldst,
      16, 0, 0);
}

// ---------------- graph preprocessing ----------------

__global__ void zero_kernel(int* p, int n) {
  int i = blockIdx.x * blockDim.x + threadIdx.x;
  if (i < n) p[i] = 0;
}

// edge_index layout [2, E] row-major: sources [0..E), destinations [E..2E)
__global__ void count_kernel(const int* __restrict__ ei, int E, int* __restrict__ cnt) {
  int i = blockIdx.x * blockDim.x + threadIdx.x;
  if (i < E) atomicAdd(&cnt[ei[E + i]], 1);
}

__global__ void dinv_kernel(const int* __restrict__ cnt, float* __restrict__ dinv, int n) {
  int i = blockIdx.x * blockDim.x + threadIdx.x;
  if (i < n) dinv[i] = rsqrtf((float)(cnt[i] + 1));  // +1 self-loop; deg >= 1
}

// exclusive scan of (cnt[i]+1) over N=1700 -> off[0..N]; single block
__global__ __launch_bounds__(1024) void scan_kernel(const int* __restrict__ cnt, int n,
                                                    int* __restrict__ off) {
  __shared__ int s[2048];
  int t = threadIdx.x;
  for (int i = t; i < 2048; i += 1024) s[i] = (i < n) ? (cnt[i] + 1) : 0;
  for (int d = 1; d < 2048; d <<= 1) {
    __syncthreads();
    int idx = (t + 1) * (d << 1) - 1;
    if (idx < 2048) s[idx] += s[idx - d];
  }
  __syncthreads();
  if (t == 0) s[2047] = 0;
  for (int d = 1024; d >= 1; d >>= 1) {
    __syncthreads();
    int idx = (t + 1) * (d << 1) - 1;
    if (idx < 2048) { int tmp = s[idx - d]; s[idx - d] = s[idx]; s[idx] += tmp; }
  }
  __syncthreads();
  for (int i = t; i <= n; i += 1024) off[i] = s[i];
}

__global__ void fill_kernel(const int* __restrict__ ei, int E, int n,
                            const float* __restrict__ dinv, const int* __restrict__ off,
                            int* __restrict__ cursor, int* __restrict__ srcv,
                            float* __restrict__ wv) {
  int i = blockIdx.x * blockDim.x + threadIdx.x;
  if (i >= E + n) return;
  int s, d;
  if (i < E) { s = ei[i]; d = ei[E + i]; } else { s = d = i - E; }
  float w = dinv[s] * dinv[d];
  int p = atomicAdd(&cursor[d], 1);
  int idx = off[d] + p;
  srcv[idx] = s;
  wv[idx] = w;
}

// W f32 [k][n] -> Wtt bf16 K-tiled [s][n][32]  (s = k/32)
__global__ void transpose_kernel(const float* __restrict__ W,
                                 unsigned short* __restrict__ Wtt) {
  int i = blockIdx.x * 256 + threadIdx.x;  // 65536 elems
  int k = i >> 8, n = i & 255;
  Wtt[(((k >> 5) << 8) + n) * 32 + (k & 31)] = f2bf(W[i]);
}

// ---------------- GEMM: H[m][256] = A[m][256] @ W, full-N tile ----------------
// Block = 128 rows x 256 cols. A-tile (64KB, [s][row][32] bf16) staged up-front
// (16 global_load_lds per thread, AF32: load+convert+ds_write), then ONE barrier,
// then fully-unrolled K loop: A-frags from LDS, B-frags from global (L2-resident
// Wtt [s][n][32]) — no K-loop barriers. Rows indexed m = n*NB + b ([node][batch]);
// AF32 reads x in [b][n] layout.

template <bool AF32>
__global__ __launch_bounds__(256, 2) void gemm_fullN(const void* __restrict__ Ap,
                                                     const unsigned short* __restrict__ Wtt,
                                                     unsigned short* __restrict__ H) {
  __shared__ __align__(16) unsigned short As[8 * 128 * 32];  // 64 KB
  const int t = threadIdx.x;
  const int row0 = blockIdx.x * 128;

  if (AF32) {
    const float* A = (const float*)Ap;
#pragma unroll
    for (int j = 0; j < 16; j++) {
      const int c = t + j * 256;                     // 16B-chunk id
      const int u = c & 3, row = (c >> 2) & 127, s = c >> 9;
      const int g = row0 + row;
      const int n = g >> 6, b = g & (NB - 1);        // m = n*64 + b
      const float* src = A + ((size_t)b * NNODES + n) * CDIM + s * 32 + u * 8;
      float4 f0 = *(const float4*)src;
      float4 f1 = *(const float4*)(src + 4);
      bf16x8 pk;
      pk[0] = (short)f2bf(f0.x); pk[1] = (short)f2bf(f0.y);
      pk[2] = (short)f2bf(f0.z); pk[3] = (short)f2bf(f0.w);
      pk[4] = (short)f2bf(f1.x); pk[5] = (short)f2bf(f1.y);
      pk[6] = (short)f2bf(f1.z); pk[7] = (short)f2bf(f1.w);
      *(bf16x8*)((char*)As + (size_t)c * 16) = pk;
    }
  } else {
    const unsigned short* A = (const unsigned short*)Ap;
#pragma unroll
    for (int j = 0; j < 16; j++) {
      const int c = t + j * 256;
      const int u = c & 3, row = (c >> 2) & 127, s = c >> 9;
      async_copy16(A + (size_t)(row0 + row) * CDIM + s * 32 + u * 8,
                   (char*)As + (size_t)c * 16);
    }
  }
  __syncthreads();  // the only barrier

  const int lane = t & 63, w = t >> 6;
  const int wm = (w & 1) * 64, wn = (w >> 1) * 128;
  const int rl = lane & 15, q = lane >> 4;
  f32x4 acc[4][8];
#pragma unroll
  for (int mi = 0; mi < 4; mi++)
#pragma unroll
    for (int ni = 0; ni < 8; ni++) acc[mi][ni] = (f32x4){0.f, 0.f, 0.f, 0.f};

#pragma unroll
  for (int s = 0; s < 8; s++) {
    bf16x8 a[4];
#pragma unroll
    for (int mi = 0; mi < 4; mi++)
      a[mi] = *(const bf16x8*)((char*)As + s * 8192 + (wm + mi * 16 + rl) * 64 + q * 16);
#pragma unroll
    for (int ni = 0; ni < 8; ni++) {
      bf16x8 bfr = *(const bf16x8*)&Wtt[((s << 8) + wn + ni * 16 + rl) * 32 + (q << 3)];
#pragma unroll
      for (int mi = 0; mi < 4; mi++)
        acc[mi][ni] = __builtin_amdgcn_mfma_f32_16x16x32_bf16(a[mi], bfr, acc[mi][ni], 0, 0, 0);
    }
  }

  const int orow = q * 4;  // C/D: col=lane&15, row=(lane>>4)*4+rr
#pragma unroll
  for (int mi = 0; mi < 4; mi++) {
#pragma unroll
    for (int ni = 0; ni < 8; ni++) {
      const int col = wn + ni * 16 + rl;
#pragma unroll
      for (int rr = 0; rr < 4; rr++) {
        const int grow = row0 + wm + mi * 16 + orow + rr;
        H[(size_t)grow * CDIM + col] = f2bf(acc[mi][ni][rr]);
      }
    }
  }
}

// ---------------- aggregation: per (node, 4 batches) block ----------------
// H is [n][b][c] (m = n*NB+b). Gather rows for the 4 block-batches are 2KB
// contiguous per edge; the 16 b-group blocks of a node hit identical lines.
// Depth-1 software pipeline on the edge loop. FINAL: +f32 resid, f32 out ([b][n][c]).

template <bool FINAL>
__global__ __launch_bounds__(256) void agg_kernel(const unsigned short* __restrict__ H,
                                                  const int* __restrict__ off,
                                                  const int* __restrict__ srcv,
                                                  const float* __restrict__ wv,
                                                  const float* __restrict__ bias,
                                                  const float* __restrict__ resid,
                                                  void* __restrict__ outp) {
  const int n = blockIdx.x;
  const int b = blockIdx.y * 4 + (threadIdx.x >> 6);
  const int c = (threadIdx.x & 63) * 4;
  const int beg = off[n], end = off[n + 1];  // end > beg (self-loop guaranteed)
  const unsigned short* Hb = H + (size_t)b * CDIM + c;

  float a0 = 0.f, a1 = 0.f, a2 = 0.f, a3 = 0.f;
  int sr = srcv[beg];
  float w = wv[beg];
  uint2 v = *(const uint2*)(Hb + (size_t)sr * (NB * CDIM));
  for (int e = beg + 1; e < end; e++) {
    int sr1 = srcv[e];
    float w1 = wv[e];
    uint2 v1 = *(const uint2*)(Hb + (size_t)sr1 * (NB * CDIM));  // in flight over FMAs
    a0 += w * bf2f(v.x & 0xffffu);
    a1 += w * bf2f(v.x >> 16);
    a2 += w * bf2f(v.y & 0xffffu);
    a3 += w * bf2f(v.y >> 16);
    w = w1; v = v1;
  }
  a0 += w * bf2f(v.x & 0xffffu);
  a1 += w * bf2f(v.x >> 16);
  a2 += w * bf2f(v.y & 0xffffu);
  a3 += w * bf2f(v.y >> 16);

  float4 bv = *(const float4*)(bias + c);
  a0 += bv.x; a1 += bv.y; a2 += bv.z; a3 += bv.w;

  if (FINAL) {
    const size_t o = ((size_t)b * NNODES + n) * CDIM + c;  // [b][n][c] f32
    float4 rv = *(const float4*)(resid + o);
    a0 = fmaxf(a0 + rv.x, 0.f); a1 = fmaxf(a1 + rv.y, 0.f);
    a2 = fmaxf(a2 + rv.z, 0.f); a3 = fmaxf(a3 + rv.w, 0.f);
    float4 ov; ov.x = a0; ov.y = a1; ov.z = a2; ov.w = a3;
    *(float4*)((float*)outp + o) = ov;
  } else {
    const size_t o = ((size_t)n * NB + b) * CDIM + c;      // [n][b][c] bf16
    a0 = fmaxf(a0, 0.f); a1 = fmaxf(a1, 0.f); a2 = fmaxf(a2, 0.f); a3 = fmaxf(a3, 0.f);
    uint2 ov;
    ov.x = (unsigned)f2bf(a0) | ((unsigned)f2bf(a1) << 16);
    ov.y = (unsigned)f2bf(a2) | ((unsigned)f2bf(a3) << 16);
    *(uint2*)((unsigned short*)outp + o) = ov;
  }
}

// ---------------- launch ----------------

extern "C" void kernel_launch(void* const* d_in, const int* in_sizes, int n_in,
                              void* d_out, int out_size, void* d_ws, size_t ws_size,
                              hipStream_t stream) {
  const float* x  = (const float*)d_in[0];
  const float* W1 = (const float*)d_in[1];
  const float* b1 = (const float*)d_in[2];
  const float* W2 = (const float*)d_in[3];
  const float* b2 = (const float*)d_in[4];
  const float* W3 = (const float*)d_in[5];
  const float* b3 = (const float*)d_in[6];
  const int* esp = (const int*)d_in[7];
  const int* etm = (const int*)d_in[8];

  const int Esp = in_sizes[7] / 2;
  const int Etm = in_sizes[8] / 2;
  const int M = NB * NNODES;  // 108800

  char* ws = (char*)d_ws;
  size_t woff = 0;
  auto alloc = [&](size_t bytes) -> void* {
    void* p = ws + woff;
    woff = (woff + bytes + 255) & ~(size_t)255;
    return p;
  };

  unsigned short* H   = (unsigned short*)alloc((size_t)M * CDIM * 2);  // 55.7 MB
  unsigned short* Act = (unsigned short*)alloc((size_t)M * CDIM * 2);  // 55.7 MB
  unsigned short* Wtt = (unsigned short*)alloc((size_t)3 * CDIM * CDIM * 2);
  int* zero_base = (int*)alloc((size_t)4 * NNODES * sizeof(int));
  int* cnt_sp = zero_base;
  int* cur_sp = zero_base + NNODES;
  int* cnt_tm = zero_base + 2 * NNODES;
  int* cur_tm = zero_base + 3 * NNODES;
  int* off_sp = (int*)alloc((NNODES + 1) * sizeof(int));
  int* off_tm = (int*)alloc((NNODES + 1) * sizeof(int));
  float* dinv_sp = (float*)alloc(NNODES * sizeof(float));
  float* dinv_tm = (float*)alloc(NNODES * sizeof(float));
  int*   src_sp = (int*)alloc((size_t)(Esp + NNODES) * sizeof(int));
  float* wgt_sp = (float*)alloc((size_t)(Esp + NNODES) * sizeof(float));
  int*   src_tm = (int*)alloc((size_t)(Etm + NNODES) * sizeof(int));
  float* wgt_tm = (float*)alloc((size_t)(Etm + NNODES) * sizeof(float));

  zero_kernel<<<(4 * NNODES + 255) / 256, 256, 0, stream>>>(zero_base, 4 * NNODES);
  transpose_kernel<<<256, 256, 0, stream>>>(W1, Wtt);
  transpose_kernel<<<256, 256, 0, stream>>>(W2, Wtt + CDIM * CDIM);
  transpose_kernel<<<256, 256, 0, stream>>>(W3, Wtt + 2 * CDIM * CDIM);
  count_kernel<<<(Esp + 255) / 256, 256, 0, stream>>>(esp, Esp, cnt_sp);
  count_kernel<<<(Etm + 255) / 256, 256, 0, stream>>>(etm, Etm, cnt_tm);
  dinv_kernel<<<(NNODES + 255) / 256, 256, 0, stream>>>(cnt_sp, dinv_sp, NNODES);
  dinv_kernel<<<(NNODES + 255) / 256, 256, 0, stream>>>(cnt_tm, dinv_tm, NNODES);
  scan_kernel<<<1, 1024, 0, stream>>>(cnt_sp, NNODES, off_sp);
  scan_kernel<<<1, 1024, 0, stream>>>(cnt_tm, NNODES, off_tm);
  fill_kernel<<<(Esp + NNODES + 255) / 256, 256, 0, stream>>>(esp, Esp, NNODES, dinv_sp,
                                                              off_sp, cur_sp, src_sp, wgt_sp);
  fill_kernel<<<(Etm + NNODES + 255) / 256, 256, 0, stream>>>(etm, Etm, NNODES, dinv_tm,
                                                              off_tm, cur_tm, src_tm, wgt_tm);

  const int nblk = M / 128;  // 850
  dim3 agrid(NNODES, NB / 4);

  // layer 1 (spatial):  H = x@W1 ; Act = relu(Â_sp H + b1)
  gemm_fullN<true><<<nblk, 256, 0, stream>>>(x, Wtt, H);
  agg_kernel<false><<<agrid, 256, 0, stream>>>(H, off_sp, src_sp, wgt_sp, b1, nullptr, Act);
  // layer 2 (temporal)
  gemm_fullN<false><<<nblk, 256, 0, stream>>>(Act, Wtt + CDIM * CDIM, H);
  agg_kernel<false><<<agrid, 256, 0, stream>>>(H, off_tm, src_tm, wgt_tm, b2, nullptr, Act);
  // layer 3 (spatial) + residual -> f32 out
  gemm_fullN<false><<<nblk, 256, 0, stream>>>(Act, Wtt + 2 * CDIM * CDIM, H);
  agg_kernel<true><<<agrid, 256, 0, stream>>>(H, off_sp, src_sp, wgt_sp, b3, x, d_out);
}